// Round 12
// baseline (102.318 us; speedup 1.0000x reference)
//
#include <hip/hip_runtime.h>

// ============================================================================
// ROUND 12 = DUAL MEASUREMENT ROUND.
//  - ta_convert body rep x16 (asm memory clobber per rep; idempotent stores)
//  - ta_tanh_main inner loop rep x8 (accumulate, scale 0.25 at end; clobber
//    per rep so LDS/global re-loads are not hoisted)
// Both dispatches exceed the ~40us fillBuffer rows -> real counters in top-5.
// GEMM unchanged (measured 2.5us in R6).
// ============================================================================

#define BB 16
#define TV 256
#define TS 32
#define DD 512

typedef float    floatx4  __attribute__((ext_vector_type(4)));
typedef short    short8   __attribute__((ext_vector_type(8)));
typedef unsigned short ushort8 __attribute__((ext_vector_type(8)));

#define TANH_SCALE 2.885390082f   // 2*log2(e): tanh(y)=1-2/(exp2(2y*log2e)+1)

static __device__ __forceinline__ unsigned short f2bf(float f) {
    unsigned int u = __float_as_uint(f);
    u += 0x7FFFu + ((u >> 16) & 1u);   // RNE (inputs finite)
    return (unsigned short)(u >> 16);
}

// ---------------------------------------------------------------------------
// Pass 1: convert f32 -> bf16.  REP x16 for measurement.
// ---------------------------------------------------------------------------
__global__ __launch_bounds__(256) void ta_convert(
    const float* __restrict__ video, const float* __restrict__ sent,
    const float* __restrict__ w1,    const float* __restrict__ w2,
    unsigned short* __restrict__ vb, unsigned short* __restrict__ sb,
    unsigned short* __restrict__ w1b, unsigned short* __restrict__ w2b)
{
    const int NV = BB * TV * DD, NS = BB * TS * DD, NW = DD * DD;
    const int base = (blockIdx.x * 256 + threadIdx.x) * 8;
    const float* src; unsigned short* dst; int off;
    if      (base < NV)           { src = video; dst = vb;  off = base; }
    else if (base < NV + NS)      { src = sent;  dst = sb;  off = base - NV; }
    else if (base < NV + NS + NW) { src = w1;    dst = w1b; off = base - NV - NS; }
    else                          { src = w2;    dst = w2b; off = base - NV - NS - NW; }
#pragma unroll 1
    for (int rep = 0; rep < 16; ++rep) {   // MEASUREMENT rep (idempotent)
        const float4 a = *(const float4*)(src + off);
        const float4 b = *(const float4*)(src + off + 4);
        ushort8 o;
        o[0] = f2bf(a.x); o[1] = f2bf(a.y); o[2] = f2bf(a.z); o[3] = f2bf(a.w);
        o[4] = f2bf(b.x); o[5] = f2bf(b.y); o[6] = f2bf(b.z); o[7] = f2bf(b.w);
        *(ushort8*)(dst + off) = o;
        asm volatile("" ::: "memory");     // defeat LICM / store merge
    }
}

// ---------------------------------------------------------------------------
// Pass 2: merged bf16-MFMA NT GEMM (unchanged from R11, measured ~2.5us).
// ---------------------------------------------------------------------------
__global__ __launch_bounds__(256) void ta_mfma_gemm(
    const unsigned short* __restrict__ vb, const unsigned short* __restrict__ w1b,
    const float* __restrict__ b1,          const float* __restrict__ vmask,
    unsigned short* __restrict__ tmp1h,
    const unsigned short* __restrict__ sb, const unsigned short* __restrict__ w2b,
    const float* __restrict__ smask,       unsigned short* __restrict__ tmp2h,
    const float* __restrict__ wt,          float* __restrict__ wsum)
{
    const int t = threadIdx.x;

    if (blockIdx.x == 0 && t < 64) {
        float v = 0.f;
        for (int i = t; i < DD; i += 64) v += wt[i];
        for (int off = 32; off; off >>= 1) v += __shfl_down(v, off);
        if (t == 0) wsum[0] = v;
    }

    const bool g2 = (blockIdx.x >= 512);
    const int bid = g2 ? (int)blockIdx.x - 512 : (int)blockIdx.x;
    const unsigned short* __restrict__ A = g2 ? sb    : vb;
    const unsigned short* __restrict__ W = g2 ? w2b   : w1b;
    const float* __restrict__ rm         = g2 ? smask : vmask;
    const int m0 = (g2 ? (bid & 7)  : (bid & 63)) * 64;
    const int n0 = (g2 ? (bid >> 3) : (bid >> 6)) * 64;

    __shared__ unsigned short As[2][4096];
    __shared__ unsigned short Bs[2][4096];

    const int lane = t & 63;
    const int wid  = t >> 6;
    const int wm   = wid >> 1, wn = wid & 1;
    const int lr   = lane & 15, kg = lane >> 4;

    const int r0 = t >> 3,          g0c = (t & 7) ^ (r0 & 7);
    const int r1 = (t + 256) >> 3,  g1c = (t & 7) ^ (r1 & 7);
    const unsigned short* a0p = A + (size_t)(m0 + r0) * DD + g0c * 8;
    const unsigned short* a1p = A + (size_t)(m0 + r1) * DD + g1c * 8;
    const unsigned short* w0p = W + (size_t)(n0 + r0) * DD + g0c * 8;
    const unsigned short* w1p = W + (size_t)(n0 + r1) * DD + g1c * 8;
    const int l0 = t * 8;
    const int l1 = (t + 256) * 8;

#define TA_STAGE(buf, koff) do {                                               \
    __builtin_amdgcn_global_load_lds(                                          \
        (const __attribute__((address_space(1))) void*)(a0p + (koff)),         \
        (__attribute__((address_space(3))) void*)&As[buf][l0], 16, 0, 0);      \
    __builtin_amdgcn_global_load_lds(                                          \
        (const __attribute__((address_space(1))) void*)(a1p + (koff)),         \
        (__attribute__((address_space(3))) void*)&As[buf][l1], 16, 0, 0);      \
    __builtin_amdgcn_global_load_lds(                                          \
        (const __attribute__((address_space(1))) void*)(w0p + (koff)),         \
        (__attribute__((address_space(3))) void*)&Bs[buf][l0], 16, 0, 0);      \
    __builtin_amdgcn_global_load_lds(                                          \
        (const __attribute__((address_space(1))) void*)(w1p + (koff)),         \
        (__attribute__((address_space(3))) void*)&Bs[buf][l1], 16, 0, 0);      \
  } while (0)

    floatx4 acc[2][2] = {};

    const int ml0 = wm * 32 + lr, ml1 = ml0 + 16;
    const int nl0 = wn * 32 + lr, nl1 = nl0 + 16;
    const int sa0 = ml0 * 64, sa1 = ml1 * 64;
    const int sb0 = nl0 * 64, sb1 = nl1 * 64;
    const int xa = ml0 & 7, xb = nl0 & 7;

    TA_STAGE(0, 0);
    __syncthreads();

    int cur = 0;
    for (int step = 0; step < 8; ++step) {
        if (step < 7) TA_STAGE(cur ^ 1, (step + 1) * 64);
#pragma unroll
        for (int kk = 0; kk < 2; ++kk) {
            const int kc = kk * 4 + kg;
            short8 a0 = *(const short8*)&As[cur][sa0 + ((kc ^ xa) << 3)];
            short8 a1 = *(const short8*)&As[cur][sa1 + ((kc ^ xa) << 3)];
            short8 b0 = *(const short8*)&Bs[cur][sb0 + ((kc ^ xb) << 3)];
            short8 b1 = *(const short8*)&Bs[cur][sb1 + ((kc ^ xb) << 3)];
            acc[0][0] = __builtin_amdgcn_mfma_f32_16x16x32_bf16(a0, b0, acc[0][0], 0, 0, 0);
            acc[0][1] = __builtin_amdgcn_mfma_f32_16x16x32_bf16(a0, b1, acc[0][1], 0, 0, 0);
            acc[1][0] = __builtin_amdgcn_mfma_f32_16x16x32_bf16(a1, b0, acc[1][0], 0, 0, 0);
            acc[1][1] = __builtin_amdgcn_mfma_f32_16x16x32_bf16(a1, b1, acc[1][1], 0, 0, 0);
        }
        __syncthreads();
        cur ^= 1;
    }
#undef TA_STAGE

#pragma unroll
    for (int fm = 0; fm < 2; ++fm)
#pragma unroll
        for (int fn = 0; fn < 2; ++fn)
#pragma unroll
            for (int r = 0; r < 4; ++r) {
                const int m = m0 + wm * 32 + fm * 16 + kg * 4 + r;
                const int n = n0 + wn * 32 + fn * 16 + lr;
                const float mk = rm[m] * TANH_SCALE;
                float z = g2 ? (acc[fm][fn][r] * mk)
                             : (acc[fm][fn][r] + b1[n]) * mk;
                z = fminf(fmaxf(z, -30.f), 30.f);
                const float e = __builtin_amdgcn_exp2f(z);
                if (!g2) {
                    tmp1h[(size_t)m * DD + n] = f2bf(e);
                } else {
                    const int bb = m >> 5, ss = m & 31;
                    tmp2h[(size_t)bb * 16384 + (size_t)(ss >> 4) * 8192
                          + (size_t)(n >> 1) * 32 + (ss & 15) * 2 + (n & 1)] = f2bf(e);
                }
            }
}

// ---------------------------------------------------------------------------
// Pass 3: R11 structure, inner loop REP x8 (accumulate, scale 0.25 at end).
// ---------------------------------------------------------------------------
__global__ __launch_bounds__(256) void ta_tanh_main(
    const unsigned short* __restrict__ tmp1h, // [B*TV][D] bf16 = E1
    const unsigned short* __restrict__ tmp2h, // [B][2][D/2][16][2] bf16 = E2
    const float* __restrict__ wt,             // [D]
    const float* __restrict__ wsum,           // [1]
    const float* __restrict__ vmask,          // [B*TV]
    const float* __restrict__ smask,          // [B*TS]
    float* __restrict__ out)                  // [B][TV][TS]
{
    __shared__ unsigned int e2u[4096];   // 16 KB
    __shared__ float part[512];          // 2 KB

    const int t   = threadIdx.x;
    const int bid = blockIdx.x;
    const int b   = bid >> 7;
    const int vt  = (bid >> 1) & 63;
    const int sh  = bid & 1;
    const int v0  = vt << 2;

    {
        const ushort8* src = (const ushort8*)(tmp2h + (size_t)b * 16384 + sh * 8192);
        ushort8* dst = (ushort8*)e2u;
#pragma unroll
        for (int i = 0; i < 4; ++i) dst[t + 256 * i] = src[t + 256 * i];
    }
    __syncthreads();

    const int s  = t & 15;
    const int vi = (t >> 4) & 1;
    const int q  = t >> 5;

    const unsigned short* __restrict__ e1lo =
        tmp1h + (size_t)(b * TV + v0 + vi) * DD + q * 64;
    const unsigned short* __restrict__ e1hi = e1lo + 2 * DD;
    const float* __restrict__ wtp = wt + q * 64;
    const int ubase = (q * 32) * 16 + s;

    floatx4 alo = {0.f, 0.f, 0.f, 0.f};
    floatx4 ahi = {0.f, 0.f, 0.f, 0.f};
#pragma unroll 1
    for (int rep = 0; rep < 8; ++rep) {   // MEASUREMENT rep (accumulate x8)
        asm volatile("" ::: "memory");     // force faithful re-loads each rep
#pragma unroll 2
        for (int i = 0; i < 8; ++i) {
            const int ub = ubase + i * 64;
            const unsigned u0 = e2u[ub];
            const unsigned u1 = e2u[ub + 16];
            const unsigned u2 = e2u[ub + 32];
            const unsigned u3 = e2u[ub + 48];
            ushort8 l8 = *(const ushort8*)(e1lo + i * 8);
            ushort8 h8 = *(const ushort8*)(e1hi + i * 8);
            floatx4 wa = *(const floatx4*)(wtp + i * 8);
            floatx4 wb = *(const floatx4*)(wtp + i * 8 + 4);
            const float e2v[8] = {
                __uint_as_float(u0 << 16), __uint_as_float(u0 & 0xffff0000u),
                __uint_as_float(u1 << 16), __uint_as_float(u1 & 0xffff0000u),
                __uint_as_float(u2 << 16), __uint_as_float(u2 & 0xffff0000u),
                __uint_as_float(u3 << 16), __uint_as_float(u3 & 0xffff0000u)
            };
#pragma unroll
            for (int j = 0; j < 4; ++j) {
                const float xl = __uint_as_float((unsigned)l8[j] << 16);
                const float xh = __uint_as_float((unsigned)h8[j] << 16);
                const float dlo = fmaf(xl, e2v[j], 1.f);
                const float dhi = fmaf(xh, e2v[j], 1.f);
                const float inv = __builtin_amdgcn_rcpf(dlo * dhi);
                alo[j] = fmaf(wa[j], dhi * inv, alo[j]);
                ahi[j] = fmaf(wa[j], dlo * inv, ahi[j]);
            }
#pragma unroll
            for (int j = 0; j < 4; ++j) {
                const float xl = __uint_as_float((unsigned)l8[j + 4] << 16);
                const float xh = __uint_as_float((unsigned)h8[j + 4] << 16);
                const float dlo = fmaf(xl, e2v[j + 4], 1.f);
                const float dhi = fmaf(xh, e2v[j + 4], 1.f);
                const float inv = __builtin_amdgcn_rcpf(dlo * dhi);
                alo[j] = fmaf(wb[j], dhi * inv, alo[j]);
                ahi[j] = fmaf(wb[j], dlo * inv, ahi[j]);
            }
        }
    }

    part[(vi    ) * 128 + s * 8 + q] = (alo[0] + alo[1]) + (alo[2] + alo[3]);
    part[(vi + 2) * 128 + s * 8 + q] = (ahi[0] + ahi[1]) + (ahi[2] + ahi[3]);
    __syncthreads();

    if (t < 64) {
        const int vrow = t >> 4, s2 = t & 15;
        const floatx4 p0 = *(const floatx4*)&part[vrow * 128 + s2 * 8];
        const floatx4 p1 = *(const floatx4*)&part[vrow * 128 + s2 * 8 + 4];
        const float sum8 = ((p0[0] + p0[1]) + (p0[2] + p0[3]))
                         + ((p1[0] + p1[1]) + (p1[2] + p1[3]));
        const int v  = v0 + vrow;
        const int sg = sh * 16 + s2;
        const float pm = vmask[b * TV + v] * smask[b * TS + sg];
        // sum8 = 8x true sum; out = pm*(wsum - 2*(sum8/8)) = pm*(wsum - 0.25*sum8)
        out[((size_t)b * TV + v) * TS + sg] = pm * (wsum[0] - 0.25f * sum8);
    }
}

// ---------------------------------------------------------------------------
extern "C" void kernel_launch(void* const* d_in, const int* in_sizes, int n_in,
                              void* d_out, int out_size, void* d_ws, size_t ws_size,
                              hipStream_t stream)
{
    const float* video = (const float*)d_in[0];
    const float* vmask = (const float*)d_in[1];
    const float* sent  = (const float*)d_in[2];
    const float* smask = (const float*)d_in[3];
    const float* w1    = (const float*)d_in[4];
    const float* b1    = (const float*)d_in[5];
    const float* w2    = (const float*)d_in[6];
    const float* wt    = (const float*)d_in[7];
    float* out = (float*)d_out;

    const size_t NV = (size_t)BB * TV * DD, NS = (size_t)BB * TS * DD, NW = (size_t)DD * DD;

    unsigned short* tmp1h = (unsigned short*)d_ws;   // 4 MB bf16 (E1)
    unsigned short* tmp2h = tmp1h + NV;              // 512 KB bf16 (E2)
    unsigned short* vb    = tmp2h + NS;
    unsigned short* sb    = vb + NV;
    unsigned short* w1b   = sb + NS;
    unsigned short* w2b   = w1b + NW;
    float* wsum           = (float*)(w2b + NW);

    const int total8 = (int)((NV + NS + 2 * NW) / 8);
    ta_convert<<<dim3(total8 / 256), dim3(256), 0, stream>>>(
        video, sent, w1, w2, vb, sb, w1b, w2b);
    ta_mfma_gemm<<<dim3(512 + 64), dim3(256), 0, stream>>>(
        vb, w1b, b1, vmask, tmp1h, sb, w2b, smask, tmp2h, wt, wsum);
    ta_tanh_main<<<dim3(BB * (TV / 4) * 2), dim3(256), 0, stream>>>(
        tmp1h, tmp2h, wt, wsum, vmask, smask, out);
}

// Round 13
// 35.281 us; speedup vs baseline: 2.9001x; 2.9001x over previous
//
#include <hip/hip_runtime.h>

#define BB 16
#define TV 256
#define TS 32
#define DD 512

typedef float    floatx4  __attribute__((ext_vector_type(4)));
typedef short    short8   __attribute__((ext_vector_type(8)));
typedef unsigned short ushort8 __attribute__((ext_vector_type(8)));

#define TANH_SCALE 2.885390082f   // 2*log2(e): tanh(y)=1-2/(exp2(2y*log2e)+1)

static __device__ __forceinline__ unsigned short f2bf(float f) {
    unsigned int u = __float_as_uint(f);
    u += 0x7FFFu + ((u >> 16) & 1u);   // RNE (inputs finite)
    return (unsigned short)(u >> 16);
}

// ---------------------------------------------------------------------------
// Pass 1: convert video/sent/w1/w2 f32 -> bf16 once (memory-bound, ~4us).
// ---------------------------------------------------------------------------
__global__ __launch_bounds__(256) void ta_convert(
    const float* __restrict__ video, const float* __restrict__ sent,
    const float* __restrict__ w1,    const float* __restrict__ w2,
    unsigned short* __restrict__ vb, unsigned short* __restrict__ sb,
    unsigned short* __restrict__ w1b, unsigned short* __restrict__ w2b)
{
    const int NV = BB * TV * DD, NS = BB * TS * DD, NW = DD * DD;
    const int base = (blockIdx.x * 256 + threadIdx.x) * 8;
    const float* src; unsigned short* dst; int off;
    if      (base < NV)           { src = video; dst = vb;  off = base; }
    else if (base < NV + NS)      { src = sent;  dst = sb;  off = base - NV; }
    else if (base < NV + NS + NW) { src = w1;    dst = w1b; off = base - NV - NS; }
    else                          { src = w2;    dst = w2b; off = base - NV - NS - NW; }
    const float4 a = *(const float4*)(src + off);
    const float4 b = *(const float4*)(src + off + 4);
    ushort8 o;
    o[0] = f2bf(a.x); o[1] = f2bf(a.y); o[2] = f2bf(a.z); o[3] = f2bf(a.w);
    o[4] = f2bf(b.x); o[5] = f2bf(b.y); o[6] = f2bf(b.z); o[7] = f2bf(b.w);
    *(ushort8*)(dst + off) = o;
}

// ---------------------------------------------------------------------------
// Pass 2: merged bf16-MFMA NT GEMM (measured ~2.5us). Epilogues store
// FACTORED exps as bf16, z clamped +-30 (tanh saturated -> exact):
// g1: tmp1h[m][n] = bf16(exp2(clamp((val+b1[n])*vmask[m]*C)))
// g2: tmp2h layout [b][s>>4][n>>1][s&15][n&1] bf16 (s-half split)
// ---------------------------------------------------------------------------
__global__ __launch_bounds__(256) void ta_mfma_gemm(
    const unsigned short* __restrict__ vb, const unsigned short* __restrict__ w1b,
    const float* __restrict__ b1,          const float* __restrict__ vmask,
    unsigned short* __restrict__ tmp1h,
    const unsigned short* __restrict__ sb, const unsigned short* __restrict__ w2b,
    const float* __restrict__ smask,       unsigned short* __restrict__ tmp2h,
    const float* __restrict__ wt,          float* __restrict__ wsum)
{
    const int t = threadIdx.x;

    if (blockIdx.x == 0 && t < 64) {
        float v = 0.f;
        for (int i = t; i < DD; i += 64) v += wt[i];
        for (int off = 32; off; off >>= 1) v += __shfl_down(v, off);
        if (t == 0) wsum[0] = v;
    }

    const bool g2 = (blockIdx.x >= 512);
    const int bid = g2 ? (int)blockIdx.x - 512 : (int)blockIdx.x;
    const unsigned short* __restrict__ A = g2 ? sb    : vb;
    const unsigned short* __restrict__ W = g2 ? w2b   : w1b;
    const float* __restrict__ rm         = g2 ? smask : vmask;
    const int m0 = (g2 ? (bid & 7)  : (bid & 63)) * 64;
    const int n0 = (g2 ? (bid >> 3) : (bid >> 6)) * 64;

    __shared__ unsigned short As[2][4096];
    __shared__ unsigned short Bs[2][4096];

    const int lane = t & 63;
    const int wid  = t >> 6;
    const int wm   = wid >> 1, wn = wid & 1;
    const int lr   = lane & 15, kg = lane >> 4;

    const int r0 = t >> 3,          g0c = (t & 7) ^ (r0 & 7);
    const int r1 = (t + 256) >> 3,  g1c = (t & 7) ^ (r1 & 7);
    const unsigned short* a0p = A + (size_t)(m0 + r0) * DD + g0c * 8;
    const unsigned short* a1p = A + (size_t)(m0 + r1) * DD + g1c * 8;
    const unsigned short* w0p = W + (size_t)(n0 + r0) * DD + g0c * 8;
    const unsigned short* w1p = W + (size_t)(n0 + r1) * DD + g1c * 8;
    const int l0 = t * 8;
    const int l1 = (t + 256) * 8;

#define TA_STAGE(buf, koff) do {                                               \
    __builtin_amdgcn_global_load_lds(                                          \
        (const __attribute__((address_space(1))) void*)(a0p + (koff)),         \
        (__attribute__((address_space(3))) void*)&As[buf][l0], 16, 0, 0);      \
    __builtin_amdgcn_global_load_lds(                                          \
        (const __attribute__((address_space(1))) void*)(a1p + (koff)),         \
        (__attribute__((address_space(3))) void*)&As[buf][l1], 16, 0, 0);      \
    __builtin_amdgcn_global_load_lds(                                          \
        (const __attribute__((address_space(1))) void*)(w0p + (koff)),         \
        (__attribute__((address_space(3))) void*)&Bs[buf][l0], 16, 0, 0);      \
    __builtin_amdgcn_global_load_lds(                                          \
        (const __attribute__((address_space(1))) void*)(w1p + (koff)),         \
        (__attribute__((address_space(3))) void*)&Bs[buf][l1], 16, 0, 0);      \
  } while (0)

    floatx4 acc[2][2] = {};

    const int ml0 = wm * 32 + lr, ml1 = ml0 + 16;
    const int nl0 = wn * 32 + lr, nl1 = nl0 + 16;
    const int sa0 = ml0 * 64, sa1 = ml1 * 64;
    const int sb0 = nl0 * 64, sb1 = nl1 * 64;
    const int xa = ml0 & 7, xb = nl0 & 7;

    TA_STAGE(0, 0);
    __syncthreads();

    int cur = 0;
    for (int step = 0; step < 8; ++step) {
        if (step < 7) TA_STAGE(cur ^ 1, (step + 1) * 64);
#pragma unroll
        for (int kk = 0; kk < 2; ++kk) {
            const int kc = kk * 4 + kg;
            short8 a0 = *(const short8*)&As[cur][sa0 + ((kc ^ xa) << 3)];
            short8 a1 = *(const short8*)&As[cur][sa1 + ((kc ^ xa) << 3)];
            short8 b0 = *(const short8*)&Bs[cur][sb0 + ((kc ^ xb) << 3)];
            short8 b1 = *(const short8*)&Bs[cur][sb1 + ((kc ^ xb) << 3)];
            acc[0][0] = __builtin_amdgcn_mfma_f32_16x16x32_bf16(a0, b0, acc[0][0], 0, 0, 0);
            acc[0][1] = __builtin_amdgcn_mfma_f32_16x16x32_bf16(a0, b1, acc[0][1], 0, 0, 0);
            acc[1][0] = __builtin_amdgcn_mfma_f32_16x16x32_bf16(a1, b0, acc[1][0], 0, 0, 0);
            acc[1][1] = __builtin_amdgcn_mfma_f32_16x16x32_bf16(a1, b1, acc[1][1], 0, 0, 0);
        }
        __syncthreads();
        cur ^= 1;
    }
#undef TA_STAGE

#pragma unroll
    for (int fm = 0; fm < 2; ++fm)
#pragma unroll
        for (int fn = 0; fn < 2; ++fn)
#pragma unroll
            for (int r = 0; r < 4; ++r) {
                const int m = m0 + wm * 32 + fm * 16 + kg * 4 + r;
                const int n = n0 + wn * 32 + fn * 16 + lr;
                const float mk = rm[m] * TANH_SCALE;
                float z = g2 ? (acc[fm][fn][r] * mk)
                             : (acc[fm][fn][r] + b1[n]) * mk;
                z = fminf(fmaxf(z, -30.f), 30.f);
                const float e = __builtin_amdgcn_exp2f(z);
                if (!g2) {
                    tmp1h[(size_t)m * DD + n] = f2bf(e);
                } else {
                    const int bb = m >> 5, ss = m & 31;
                    tmp2h[(size_t)bb * 16384 + (size_t)(ss >> 4) * 8192
                          + (size_t)(n >> 1) * 32 + (ss & 15) * 2 + (n & 1)] = f2bf(e);
                }
            }
}

// ---------------------------------------------------------------------------
// Pass 3: pairwise reduction, ALL inputs async-staged to LDS via
// global_load_lds (absorbs cold-miss latency in the DMA path instead of
// per-wave serialized stalls — the measured 12.3us fixed cost), direct rcp
// (trans pipe was idle; trans/VALU overlap measured in R8).
// Block 256 = 16s x 2vi x 8q, 2 v/thread; grid = 2048.
// LDS: E2 16KB + E1 4x520 ushort (pad -> 2-way max) + part 2KB = ~22.2KB.
// ---------------------------------------------------------------------------
__global__ __launch_bounds__(256, 6) void ta_tanh_main(
    const unsigned short* __restrict__ tmp1h, // [B*TV][D] bf16 = E1
    const unsigned short* __restrict__ tmp2h, // [B][2][D/2][16][2] bf16 = E2
    const float* __restrict__ wt,             // [D]
    const float* __restrict__ wsum,           // [1]
    const float* __restrict__ vmask,          // [B*TV]
    const float* __restrict__ smask,          // [B*TS]
    float* __restrict__ out)                  // [B][TV][TS]
{
    __shared__ unsigned int   e2u[4096];      // 16 KB: [d2 256][s16] pairs
    __shared__ unsigned short e1u[4 * 520];   // 4.06 KB (row pad 16B)
    __shared__ float part[512];               // 2 KB

    const int t   = threadIdx.x;
    const int bid = blockIdx.x;
    const int b   = bid >> 7;
    const int vt  = (bid >> 1) & 63;
    const int sh  = bid & 1;
    const int v0  = vt << 2;

    {   // async stage: E2 4x16B/thread + E1 1x16B/thread, one barrier
        const unsigned short* e2src = tmp2h + (size_t)b * 16384 + sh * 8192 + t * 8;
#pragma unroll
        for (int i = 0; i < 4; ++i) {
            __builtin_amdgcn_global_load_lds(
                (const __attribute__((address_space(1))) void*)(e2src + i * 2048),
                (__attribute__((address_space(3))) void*)&e2u[t * 4 + i * 1024], 16, 0, 0);
        }
        const int row = t >> 6, col = (t & 63) * 8;
        __builtin_amdgcn_global_load_lds(
            (const __attribute__((address_space(1))) void*)
                (tmp1h + (size_t)(b * TV + v0 + row) * DD + col),
            (__attribute__((address_space(3))) void*)&e1u[row * 520 + col], 16, 0, 0);
    }
    __syncthreads();

    const int s  = t & 15;
    const int vi = (t >> 4) & 1;
    const int q  = t >> 5;                    // 0..7, 64-d slice

    const unsigned short* __restrict__ e1lo = e1u + vi * 520 + q * 64;
    const unsigned short* __restrict__ e1hi = e1u + (vi + 2) * 520 + q * 64;
    const float* __restrict__ wtp = wt + q * 64;
    const int ubase = q * 512 + s;            // u32 idx = d2*16 + s

    floatx4 alo = {0.f, 0.f, 0.f, 0.f};
    floatx4 ahi = {0.f, 0.f, 0.f, 0.f};
#pragma unroll
    for (int i = 0; i < 8; ++i) {
        const int ub = ubase + i * 64;
        const unsigned u0 = e2u[ub];
        const unsigned u1 = e2u[ub + 16];
        const unsigned u2 = e2u[ub + 32];
        const unsigned u3 = e2u[ub + 48];
        ushort8 l8 = *(const ushort8*)(e1lo + i * 8);   // LDS b128, 2-way max
        ushort8 h8 = *(const ushort8*)(e1hi + i * 8);
        floatx4 wa = *(const floatx4*)(wtp + i * 8);    // global, broadcast
        floatx4 wb = *(const floatx4*)(wtp + i * 8 + 4);
        const float e2v[8] = {
            __uint_as_float(u0 << 16), __uint_as_float(u0 & 0xffff0000u),
            __uint_as_float(u1 << 16), __uint_as_float(u1 & 0xffff0000u),
            __uint_as_float(u2 << 16), __uint_as_float(u2 & 0xffff0000u),
            __uint_as_float(u3 << 16), __uint_as_float(u3 & 0xffff0000u)
        };
#pragma unroll
        for (int j = 0; j < 4; ++j) {
            const float xl = __uint_as_float((unsigned)l8[j] << 16);
            const float xh = __uint_as_float((unsigned)h8[j] << 16);
            const float rl = __builtin_amdgcn_rcpf(fmaf(xl, e2v[j], 1.f));
            const float rh = __builtin_amdgcn_rcpf(fmaf(xh, e2v[j], 1.f));
            alo[j] = fmaf(wa[j], rl, alo[j]);
            ahi[j] = fmaf(wa[j], rh, ahi[j]);
        }
#pragma unroll
        for (int j = 0; j < 4; ++j) {
            const float xl = __uint_as_float((unsigned)l8[j + 4] << 16);
            const float xh = __uint_as_float((unsigned)h8[j + 4] << 16);
            const float rl = __builtin_amdgcn_rcpf(fmaf(xl, e2v[j + 4], 1.f));
            const float rh = __builtin_amdgcn_rcpf(fmaf(xh, e2v[j + 4], 1.f));
            alo[j] = fmaf(wb[j], rl, alo[j]);
            ahi[j] = fmaf(wb[j], rh, ahi[j]);
        }
    }

    part[(vi    ) * 128 + s * 8 + q] = (alo[0] + alo[1]) + (alo[2] + alo[3]);
    part[(vi + 2) * 128 + s * 8 + q] = (ahi[0] + ahi[1]) + (ahi[2] + ahi[3]);
    __syncthreads();

    if (t < 64) {
        const int vrow = t >> 4, s2 = t & 15;
        const floatx4 p0 = *(const floatx4*)&part[vrow * 128 + s2 * 8];
        const floatx4 p1 = *(const floatx4*)&part[vrow * 128 + s2 * 8 + 4];
        const float sum = ((p0[0] + p0[1]) + (p0[2] + p0[3]))
                        + ((p1[0] + p1[1]) + (p1[2] + p1[3]));
        const int v  = v0 + vrow;
        const int sg = sh * 16 + s2;
        const float pm = vmask[b * TV + v] * smask[b * TS + sg];
        out[((size_t)b * TV + v) * TS + sg] = pm * (wsum[0] - 2.f * sum);
    }
}

// ---------------------------------------------------------------------------
extern "C" void kernel_launch(void* const* d_in, const int* in_sizes, int n_in,
                              void* d_out, int out_size, void* d_ws, size_t ws_size,
                              hipStream_t stream)
{
    const float* video = (const float*)d_in[0];
    const float* vmask = (const float*)d_in[1];
    const float* sent  = (const float*)d_in[2];
    const float* smask = (const float*)d_in[3];
    const float* w1    = (const float*)d_in[4];
    const float* b1    = (const float*)d_in[5];
    const float* w2    = (const float*)d_in[6];
    const float* wt    = (const float*)d_in[7];
    float* out = (float*)d_out;

    const size_t NV = (size_t)BB * TV * DD, NS = (size_t)BB * TS * DD, NW = (size_t)DD * DD;

    unsigned short* tmp1h = (unsigned short*)d_ws;   // 4 MB bf16 (E1)
    unsigned short* tmp2h = tmp1h + NV;              // 512 KB bf16 (E2)
    unsigned short* vb    = tmp2h + NS;
    unsigned short* sb    = vb + NV;
    unsigned short* w1b   = sb + NS;
    unsigned short* w2b   = w1b + NW;
    float* wsum           = (float*)(w2b + NW);

    const int total8 = (int)((NV + NS + 2 * NW) / 8);
    ta_convert<<<dim3(total8 / 256), dim3(256), 0, stream>>>(
        video, sent, w1, w2, vb, sb, w1b, w2b);
    ta_mfma_gemm<<<dim3(512 + 64), dim3(256), 0, stream>>>(
        vb, w1b, b1, vmask, tmp1h, sb, w2b, smask, tmp2h, wt, wsum);
    ta_tanh_main<<<dim3(BB * (TV / 4) * 2), dim3(256), 0, stream>>>(
        tmp1h, tmp2h, wt, wsum, vmask, smask, out);
}